// Round 1
// baseline (265.762 us; speedup 1.0000x reference)
//
#include <hip/hip_runtime.h>

// ShapeletLearner: B=2048, Q=1024, K=32, L=64, S=993
// out[b,c] = sum_l min_s( wsq[b,s] - (2/K) * dot(ts[b,s:s+K], sh[l]) + ssq[l] ) * fcw[c,l] + fcb[c]

#define B_  2048
#define Q_  1024
#define K_  32
#define L_  64
#define S_  993
#define SP  1024   // padded S (multiple of 128)
#define TSB 1056   // padded ts length (1024 + 32 pad, /4 aligned)

__global__ __launch_bounds__(256, 4)
void shapelet_kernel(const float* __restrict__ ts,
                     const float* __restrict__ shp,
                     const float* __restrict__ fcw,
                     const float* __restrict__ fcb,
                     float* __restrict__ out)
{
    __shared__ __align__(16) float lts[TSB];          // ts row, zero-padded
    __shared__ float shRaw[L_][K_ + 1];               // +1 pad: conflict-free transpose
    __shared__ __align__(16) float shT[K_][L_];       // transposed shapelets
    __shared__ float ssq[L_];
    __shared__ float wsq[SP];
    __shared__ float red[16][L_];

    const int tid = threadIdx.x;
    const int b   = blockIdx.x;

    // ---- stage ts row (coalesced float4) + zero pad ----
    {
        const float4* g  = (const float4*)(ts + (size_t)b * Q_);
        float4*       l4 = (float4*)lts;
        l4[tid] = g[tid];                              // 256 threads x 16B = 1024 floats
        if (tid < (TSB - Q_) / 4)
            l4[Q_ / 4 + tid] = make_float4(0.f, 0.f, 0.f, 0.f);
    }
    // ---- stage shapelets raw (coalesced reads, conflict-free writes) ----
    for (int i = tid; i < L_ * K_; i += 256)
        shRaw[i >> 5][i & 31] = shp[i];
    __syncthreads();

    // ---- transpose to shT (padded shRaw -> conflict-free both sides) ----
    {
        const int l  = tid & 63;
        const int k0 = (tid >> 6) * 8;
        #pragma unroll
        for (int kk = 0; kk < 8; ++kk)
            shT[k0 + kk][l] = shRaw[l][k0 + kk];
    }
    // ---- ssq[l] ----
    if (tid < L_) {
        float s = 0.f;
        #pragma unroll
        for (int k = 0; k < K_; ++k) { float v = shRaw[tid][k]; s = fmaf(v, v, s); }
        ssq[tid] = s * (1.0f / K_);
    }
    // ---- wsq[s] (1e30 for padded s -> never wins the min) ----
    for (int s = tid; s < SP; s += 256) {
        float a = 0.f;
        #pragma unroll
        for (int k = 0; k < K_; ++k) { float v = lts[s + k]; a = fmaf(v, v, a); }
        wsq[s] = (s < S_) ? a * (1.0f / K_) : 1e30f;
    }
    __syncthreads();

    // ---- main loop: each thread = 8 s x 4 l tile ----
    const int   lt  = tid & 15;        // l-tile 0..15
    const int   sg  = tid >> 4;        // s-group 0..15 (each covers 64 s-slots)
    const int   l0  = lt * 4;
    const float c2k = 2.0f / K_;
    float m0 = 1e30f, m1 = 1e30f, m2 = 1e30f, m3 = 1e30f;

    #pragma unroll 1
    for (int chunk = 0; chunk < 8; ++chunk) {
        const int s0 = sg * 64 + chunk * 8;

        // preload sliding window: ts[s0 .. s0+39]
        float w[40];
        {
            const float4* p = (const float4*)(lts + s0);   // s0 % 8 == 0 -> 16B aligned
            #pragma unroll
            for (int t = 0; t < 10; ++t) {
                float4 v = p[t];
                w[4*t+0] = v.x; w[4*t+1] = v.y; w[4*t+2] = v.z; w[4*t+3] = v.w;
            }
        }

        float acc[8][4];
        #pragma unroll
        for (int j = 0; j < 8; ++j)
            acc[j][0] = acc[j][1] = acc[j][2] = acc[j][3] = 0.f;

        #pragma unroll
        for (int k = 0; k < K_; ++k) {
            float4 sv = *(const float4*)&shT[k][l0];
            #pragma unroll
            for (int j = 0; j < 8; ++j) {
                const float wv = w[j + k];
                acc[j][0] = fmaf(wv, sv.x, acc[j][0]);
                acc[j][1] = fmaf(wv, sv.y, acc[j][1]);
                acc[j][2] = fmaf(wv, sv.z, acc[j][2]);
                acc[j][3] = fmaf(wv, sv.w, acc[j][3]);
            }
        }

        #pragma unroll
        for (int j = 0; j < 8; ++j) {
            const float base = wsq[s0 + j];
            m0 = fminf(m0, fmaf(-c2k, acc[j][0], base));
            m1 = fminf(m1, fmaf(-c2k, acc[j][1], base));
            m2 = fminf(m2, fmaf(-c2k, acc[j][2], base));
            m3 = fminf(m3, fmaf(-c2k, acc[j][3], base));
        }
    }

    red[sg][l0 + 0] = m0;
    red[sg][l0 + 1] = m1;
    red[sg][l0 + 2] = m2;
    red[sg][l0 + 3] = m3;
    __syncthreads();

    // ---- min across s-groups, + ssq, FC, wave-64 reduce ----
    if (tid < L_) {
        const int l = tid;
        float d = red[0][l];
        #pragma unroll
        for (int g = 1; g < 16; ++g) d = fminf(d, red[g][l]);
        d += ssq[l];

        float p0 = d * fcw[l];
        float p1 = d * fcw[L_ + l];
        #pragma unroll
        for (int off = 32; off > 0; off >>= 1) {
            p0 += __shfl_down(p0, off, 64);
            p1 += __shfl_down(p1, off, 64);
        }
        if (l == 0) {
            out[(size_t)b * 2 + 0] = p0 + fcb[0];
            out[(size_t)b * 2 + 1] = p1 + fcb[1];
        }
    }
}

extern "C" void kernel_launch(void* const* d_in, const int* in_sizes, int n_in,
                              void* d_out, int out_size, void* d_ws, size_t ws_size,
                              hipStream_t stream) {
    const float* ts  = (const float*)d_in[0];   // (B, Q)
    const float* shp = (const float*)d_in[1];   // (L, K)
    const float* fcw = (const float*)d_in[2];   // (2, L)
    const float* fcb = (const float*)d_in[3];   // (2,)
    float* out = (float*)d_out;                 // (B, 2)

    shapelet_kernel<<<B_, 256, 0, stream>>>(ts, shp, fcw, fcb, out);
}

// Round 2
// 81.129 us; speedup vs baseline: 3.2758x; 3.2758x over previous
//
#include <hip/hip_runtime.h>
#include <hip/hip_bf16.h>

// ShapeletLearner: B=2048, Q=1024, K=32, L=64, S=993
// dist[b,s,l] = wsq[b,s] - (2/K)*cross[b,s,l] + ssq[l];  out = min_s(dist) @ fcw^T + fcb
// cross via bf16 MFMA (Hankel GEMM), wsq/ssq exact fp32.

#define B_   2048
#define Q_   1024
#define K_   32
#define L_   64
#define S_   993
#define SP   1024          // padded S (64 tiles of 16)
#define CL   1064          // per-copy length (multiple of 8, covers pos<=1047)
#define LTSN 1064          // fp32 ts pad length

using frag_ab = __attribute__((ext_vector_type(8))) short;   // 8 bf16
using f32x4   = __attribute__((ext_vector_type(4))) float;

__global__ __launch_bounds__(256, 2)
void shapelet_mfma(const float* __restrict__ ts,
                   const float* __restrict__ shp,
                   const float* __restrict__ fcw,
                   const float* __restrict__ fcb,
                   float* __restrict__ out)
{
    __shared__ __align__(16) float           lts[LTSN];      // fp32 ts row (zero-padded)
    __shared__ __align__(16) __hip_bfloat16  tsb[8][CL];     // 8 shift-copies: tsb[c][j] = ts[c+j]
    __shared__ __align__(16) float           wsq[SP];        // 1e30 for s >= 993
    __shared__ float                         ssq[L_];
    __shared__ float                         red[4][L_];

    const int tid  = threadIdx.x;
    const int b    = blockIdx.x;
    const int lane = tid & 63;
    const int w    = tid >> 6;
    const int n    = lane & 15;      // MFMA col (s within tile) / A row (l within tile)
    const int q    = lane >> 4;      // MFMA quad

    // ---- stage ts row (1 float4/thread) + zero pad ----
    {
        const float4* g  = (const float4*)(ts + (size_t)b * Q_);
        float4*       l4 = (float4*)lts;
        l4[tid] = g[tid];
        if (tid < (LTSN - Q_) / 4)
            l4[Q_ / 4 + tid] = make_float4(0.f, 0.f, 0.f, 0.f);
    }
    // ---- ssq (exact fp32) ----
    if (tid < L_) {
        const float* sp = shp + tid * K_;
        float s = 0.f;
        #pragma unroll
        for (int k = 0; k < K_; ++k) s = fmaf(sp[k], sp[k], s);
        ssq[tid] = s * (1.0f / K_);
    }
    // ---- A fragments: shapelets, built once (A[m][k], m=lane&15, k=q*8+j) ----
    frag_ab afrag[4];
    #pragma unroll
    for (int f = 0; f < 4; ++f) {
        const float* sp = shp + (f * 16 + n) * K_ + q * 8;
        union { frag_ab v; __hip_bfloat162 p[4]; } u;
        #pragma unroll
        for (int i = 0; i < 4; ++i)
            u.p[i] = __float22bfloat162_rn(make_float2(sp[2 * i], sp[2 * i + 1]));
        afrag[f] = u.v;
    }
    __syncthreads();

    // ---- build 8 shift-copies in bf16 (pair-packed writes, 4B aligned) ----
    #pragma unroll
    for (int c = 0; c < 8; ++c) {
        for (int j = 2 * tid; j < 1048; j += 512) {
            __hip_bfloat162 v = __float22bfloat162_rn(make_float2(lts[c + j], lts[c + j + 1]));
            *(__hip_bfloat162*)&tsb[c][j] = v;
        }
    }
    // ---- wsq: 4 consecutive s per thread, sliding sum, exact fp32 ----
    {
        const int s0 = 4 * tid;
        float v[36];
        const float4* p = (const float4*)(lts + s0);
        #pragma unroll
        for (int t = 0; t < 9; ++t) {
            float4 x = p[t];
            v[4*t+0] = x.x; v[4*t+1] = x.y; v[4*t+2] = x.z; v[4*t+3] = x.w;
        }
        float sq = 0.f;
        #pragma unroll
        for (int k = 0; k < K_; ++k) sq = fmaf(v[k], v[k], sq);
        float o0 = (s0 + 0 < S_) ? sq * (1.0f / K_) : 1e30f;
        sq = sq + v[32] * v[32] - v[0] * v[0];
        float o1 = (s0 + 1 < S_) ? sq * (1.0f / K_) : 1e30f;
        sq = sq + v[33] * v[33] - v[1] * v[1];
        float o2 = (s0 + 2 < S_) ? sq * (1.0f / K_) : 1e30f;
        sq = sq + v[34] * v[34] - v[2] * v[2];
        float o3 = (s0 + 3 < S_) ? sq * (1.0f / K_) : 1e30f;
        *(float4*)&wsq[s0] = make_float4(o0, o1, o2, o3);
    }
    __syncthreads();

    // ---- main loop: wave w -> s-tiles [w*16, w*16+16); maximize y = c2k*cross - wsq ----
    // B[k=q*8+j][n] = ts[s_base + n + 8q + j]; copy c = n&7 (loop-invariant), pos = 8q + (n&8) + s_base
    const float c2k = 2.0f / K_;
    const __hip_bfloat16* bsrc = &tsb[n & 7][8 * q + (n & 8)];
    float rm[4][4];
    #pragma unroll
    for (int f = 0; f < 4; ++f)
        #pragma unroll
        for (int r = 0; r < 4; ++r) rm[f][r] = -3e38f;

    #pragma unroll 2
    for (int t = w * 16; t < w * 16 + 16; ++t) {
        const int s_base = t * 16;
        frag_ab bv = *(const frag_ab*)(bsrc + s_base);
        float   nw = -wsq[s_base + n];
        #pragma unroll
        for (int f = 0; f < 4; ++f) {
            f32x4 z = {0.f, 0.f, 0.f, 0.f};
            f32x4 d = __builtin_amdgcn_mfma_f32_16x16x32_bf16(afrag[f], bv, z, 0, 0, 0);
            #pragma unroll
            for (int r = 0; r < 4; ++r)
                rm[f][r] = fmaxf(rm[f][r], fmaf(c2k, d[r], nw));
        }
    }

    // ---- reduce max across the 16 cols (lanes within quad group) ----
    #pragma unroll
    for (int f = 0; f < 4; ++f)
        #pragma unroll
        for (int r = 0; r < 4; ++r) {
            float v = rm[f][r];
            v = fmaxf(v, __shfl_xor(v, 1, 64));
            v = fmaxf(v, __shfl_xor(v, 2, 64));
            v = fmaxf(v, __shfl_xor(v, 4, 64));
            v = fmaxf(v, __shfl_xor(v, 8, 64));
            rm[f][r] = v;
        }
    if (n == 0) {
        #pragma unroll
        for (int f = 0; f < 4; ++f)
            #pragma unroll
            for (int r = 0; r < 4; ++r)
                red[w][f * 16 + q * 4 + r] = rm[f][r];
    }
    __syncthreads();

    // ---- final: combine waves, dist = ssq - ymax, FC, wave-64 reduce ----
    if (tid < L_) {
        const int l = tid;
        float y = fmaxf(fmaxf(red[0][l], red[1][l]), fmaxf(red[2][l], red[3][l]));
        float d = ssq[l] - y;
        float p0 = d * fcw[l];
        float p1 = d * fcw[L_ + l];
        #pragma unroll
        for (int off = 32; off > 0; off >>= 1) {
            p0 += __shfl_down(p0, off, 64);
            p1 += __shfl_down(p1, off, 64);
        }
        if (l == 0) {
            out[(size_t)b * 2 + 0] = p0 + fcb[0];
            out[(size_t)b * 2 + 1] = p1 + fcb[1];
        }
    }
}

extern "C" void kernel_launch(void* const* d_in, const int* in_sizes, int n_in,
                              void* d_out, int out_size, void* d_ws, size_t ws_size,
                              hipStream_t stream) {
    const float* ts  = (const float*)d_in[0];   // (B, Q) fp32
    const float* shp = (const float*)d_in[1];   // (L, K) fp32
    const float* fcw = (const float*)d_in[2];   // (2, L) fp32
    const float* fcb = (const float*)d_in[3];   // (2,)  fp32
    float* o = (float*)d_out;                   // (B, 2) fp32

    shapelet_mfma<<<B_, 256, 0, stream>>>(ts, shp, fcw, fcb, o);
}

// Round 3
// 78.923 us; speedup vs baseline: 3.3673x; 1.0279x over previous
//
#include <hip/hip_runtime.h>
#include <hip/hip_bf16.h>

// ShapeletLearner: B=2048, Q=1024, K=32, L=64, S=993
// dist[b,s,l] = wsq[b,s] - (2/K)*cross[b,s,l] + ssq[l];  out = min_s(dist) @ fcw^T + fcb
// cross via bf16 MFMA. c2k=2^-4 pre-folded into A (exact); -wsq folded into MFMA C operand.

#define B_   2048
#define Q_   1024
#define K_   32
#define L_   64
#define S_   993
#define SP   1024          // padded S (64 tiles of 16)
#define CL   1064          // per-copy length
#define LTSN 1064          // fp32 ts pad length

using frag_ab = __attribute__((ext_vector_type(8))) short;   // 8 bf16
using f32x4   = __attribute__((ext_vector_type(4))) float;

__global__ __launch_bounds__(256, 2)
void shapelet_mfma(const float* __restrict__ ts,
                   const float* __restrict__ shp,
                   const float* __restrict__ fcw,
                   const float* __restrict__ fcb,
                   float* __restrict__ out)
{
    __shared__ __align__(16) float           lts[LTSN];      // fp32 ts row (zero-padded)
    __shared__ __align__(16) __hip_bfloat16  tsb[8][CL];     // 8 shift-copies: tsb[c][j] = ts[c+j]
    __shared__ __align__(16) float           wsq[SP];        // 1e30 for s >= 993
    __shared__ float                         ssq[L_];
    __shared__ float                         red[4][L_];

    const int tid  = threadIdx.x;
    const int b    = blockIdx.x;
    const int lane = tid & 63;
    const int w    = tid >> 6;
    const int n    = lane & 15;      // MFMA col (s within tile) / A row (l within tile)
    const int q    = lane >> 4;      // MFMA quad

    // ---- prefetch FC params early (used only in epilogue; hides load latency) ----
    float fw0 = 0.f, fw1 = 0.f, fb0 = 0.f, fb1 = 0.f;
    if (tid < L_) {
        fw0 = fcw[tid];
        fw1 = fcw[L_ + tid];
        fb0 = fcb[0];
        fb1 = fcb[1];
    }

    // ---- stage ts row (1 float4/thread) + zero pad ----
    {
        const float4* g  = (const float4*)(ts + (size_t)b * Q_);
        float4*       l4 = (float4*)lts;
        l4[tid] = g[tid];
        if (tid < (LTSN - Q_) / 4)
            l4[Q_ / 4 + tid] = make_float4(0.f, 0.f, 0.f, 0.f);
    }
    // ---- ssq (exact fp32) ----
    if (tid < L_) {
        const float* sp = shp + tid * K_;
        float s = 0.f;
        #pragma unroll
        for (int k = 0; k < K_; ++k) s = fmaf(sp[k], sp[k], s);
        ssq[tid] = s * (1.0f / K_);
    }
    // ---- A fragments: shapelets * 2^-4 (exact bf16 scale), built once ----
    // A[m=lane&15][k=q*8+j]
    frag_ab afrag[4];
    #pragma unroll
    for (int f = 0; f < 4; ++f) {
        const float4* sp = (const float4*)(shp + (f * 16 + n) * K_ + q * 8);
        float4 x0 = sp[0], x1 = sp[1];
        union { frag_ab v; __hip_bfloat162 p[4]; } u;
        u.p[0] = __float22bfloat162_rn(make_float2(x0.x * 0.0625f, x0.y * 0.0625f));
        u.p[1] = __float22bfloat162_rn(make_float2(x0.z * 0.0625f, x0.w * 0.0625f));
        u.p[2] = __float22bfloat162_rn(make_float2(x1.x * 0.0625f, x1.y * 0.0625f));
        u.p[3] = __float22bfloat162_rn(make_float2(x1.z * 0.0625f, x1.w * 0.0625f));
        afrag[f] = u.v;
    }
    __syncthreads();

    // ---- build 8 bf16 shift-copies: read 10 floats once, emit 8 packed pairs ----
    for (int j = 2 * tid; j < 1048; j += 512) {
        float v[10];
        const float2* p2 = (const float2*)(lts + j);     // j even -> 8B aligned
        #pragma unroll
        for (int i = 0; i < 5; ++i) { float2 x = p2[i]; v[2*i] = x.x; v[2*i+1] = x.y; }
        #pragma unroll
        for (int c = 0; c < 8; ++c)
            *(__hip_bfloat162*)&tsb[c][j] = __float22bfloat162_rn(make_float2(v[c], v[c+1]));
    }
    // ---- wsq: 4 consecutive s per thread, sliding sum, exact fp32 ----
    {
        const int s0 = 4 * tid;
        float v[36];
        const float4* p = (const float4*)(lts + s0);
        #pragma unroll
        for (int t = 0; t < 9; ++t) {
            float4 x = p[t];
            v[4*t+0] = x.x; v[4*t+1] = x.y; v[4*t+2] = x.z; v[4*t+3] = x.w;
        }
        float sq = 0.f;
        #pragma unroll
        for (int k = 0; k < K_; ++k) sq = fmaf(v[k], v[k], sq);
        float o0 = (s0 + 0 < S_) ? sq * (1.0f / K_) : 1e30f;
        sq = sq + v[32] * v[32] - v[0] * v[0];
        float o1 = (s0 + 1 < S_) ? sq * (1.0f / K_) : 1e30f;
        sq = sq + v[33] * v[33] - v[1] * v[1];
        float o2 = (s0 + 2 < S_) ? sq * (1.0f / K_) : 1e30f;
        sq = sq + v[34] * v[34] - v[2] * v[2];
        float o3 = (s0 + 3 < S_) ? sq * (1.0f / K_) : 1e30f;
        *(float4*)&wsq[s0] = make_float4(o0, o1, o2, o3);
    }
    __syncthreads();

    // ---- main loop: wave w -> s-tiles [w*16, w*16+16) ----
    // D = (2/K)*cross - wsq  (scale in A, -wsq in C operand); maximize D.
    const __hip_bfloat16* bsrc = &tsb[n & 7][8 * q + (n & 8)];
    float rm[4][4];
    #pragma unroll
    for (int f = 0; f < 4; ++f)
        #pragma unroll
        for (int r = 0; r < 4; ++r) rm[f][r] = -3e38f;

    #pragma unroll 4
    for (int t = w * 16; t < w * 16 + 16; ++t) {
        const int s_base = t * 16;
        frag_ab bv = *(const frag_ab*)(bsrc + s_base);
        const float nw = -wsq[s_base + n];
        f32x4 cin = {nw, nw, nw, nw};
        #pragma unroll
        for (int f = 0; f < 4; ++f) {
            f32x4 d = __builtin_amdgcn_mfma_f32_16x16x32_bf16(afrag[f], bv, cin, 0, 0, 0);
            #pragma unroll
            for (int r = 0; r < 4; ++r)
                rm[f][r] = fmaxf(rm[f][r], d[r]);
        }
    }

    // ---- reduce max across the 16 cols (lanes within quad group) ----
    #pragma unroll
    for (int f = 0; f < 4; ++f)
        #pragma unroll
        for (int r = 0; r < 4; ++r) {
            float v = rm[f][r];
            v = fmaxf(v, __shfl_xor(v, 1, 64));
            v = fmaxf(v, __shfl_xor(v, 2, 64));
            v = fmaxf(v, __shfl_xor(v, 4, 64));
            v = fmaxf(v, __shfl_xor(v, 8, 64));
            rm[f][r] = v;
        }
    if (n == 0) {
        #pragma unroll
        for (int f = 0; f < 4; ++f)
            #pragma unroll
            for (int r = 0; r < 4; ++r)
                red[w][f * 16 + q * 4 + r] = rm[f][r];
    }
    __syncthreads();

    // ---- final: combine waves, dist = ssq - ymax, FC, wave-64 reduce ----
    if (tid < L_) {
        const int l = tid;
        float y = fmaxf(fmaxf(red[0][l], red[1][l]), fmaxf(red[2][l], red[3][l]));
        float d = ssq[l] - y;
        float p0 = d * fw0;
        float p1 = d * fw1;
        #pragma unroll
        for (int off = 32; off > 0; off >>= 1) {
            p0 += __shfl_down(p0, off, 64);
            p1 += __shfl_down(p1, off, 64);
        }
        if (l == 0) {
            out[(size_t)b * 2 + 0] = p0 + fb0;
            out[(size_t)b * 2 + 1] = p1 + fb1;
        }
    }
}

extern "C" void kernel_launch(void* const* d_in, const int* in_sizes, int n_in,
                              void* d_out, int out_size, void* d_ws, size_t ws_size,
                              hipStream_t stream) {
    const float* ts  = (const float*)d_in[0];   // (B, Q) fp32
    const float* shp = (const float*)d_in[1];   // (L, K) fp32
    const float* fcw = (const float*)d_in[2];   // (2, L) fp32
    const float* fcb = (const float*)d_in[3];   // (2,)  fp32
    float* o = (float*)d_out;                   // (B, 2) fp32

    shapelet_mfma<<<B_, 256, 0, stream>>>(ts, shp, fcw, fcb, o);
}